// Round 8
// baseline (4111.215 us; speedup 1.0000x reference)
//
#include <hip/hip_runtime.h>
#include <math.h>
#include <stdint.h>

#define BBOX_CLAMP 4.135166556742356f
#define SQH 0.70710678118654752f
#define SQ2 1.41421356237309515f

typedef __attribute__((ext_vector_type(8))) short s8b;
typedef __attribute__((ext_vector_type(4))) float f32x4;

__device__ __forceinline__ unsigned okey(float f){
  unsigned u = __float_as_uint(f);
  return (u & 0x80000000u) ? ~u : (u | 0x80000000u);
}
__device__ __forceinline__ unsigned short f2bf(float f){  // RNE fp32->bf16
  unsigned u = __float_as_uint(f);
  unsigned r = (u + 0x7FFFu + ((u >> 16) & 1u)) >> 16;
  return (unsigned short)r;
}
__device__ __forceinline__ float bf2f(unsigned short h){
  return __uint_as_float(((unsigned)h) << 16);
}

// ---- one-time: split stem weights into bf16 hi/lo, MFMA-B-fragment layout ----
// whi/wlo[(((tap*8+slice)*4+g)*256 + cout)*8 + j] = split of w[cout][cin=slice*32+g*8+j][tap]
__global__ void k_wsplit(const float* __restrict__ w,
                         unsigned short* __restrict__ whi, unsigned short* __restrict__ wlo){
  const int ck = blockIdx.x;          // cin*9 + tap
  const int cout = threadIdx.x;
  const int cin = ck / 9, tap = ck - cin*9;
  const float x = w[cout*2304 + ck];
  const unsigned short h = f2bf(x);
  const unsigned short lo2 = f2bf(x - bf2f(h));
  const int slice = cin >> 5, g = (cin >> 3) & 3, j = cin & 7;
  const size_t off = ((((size_t)tap*8 + slice)*4 + g)*256 + cout)*8 + j;
  whi[off] = h; wlo[off] = lo2;
}

// ---- fused stem conv3x3 (split-bf16 MFMA) + bias + relu + obj/box heads ----
// Block: 256 thr / 4 waves. Tile: 2 rows x 32 cols of pixels, all 256 couts.
// Wave w: pixel strip (row w>>1, cols (w&1)*16..+15). mfma_f32_16x16x32_bf16:
// A[pix][cin]: lane holds row=l&15, k=(l>>4)*8+j ; B[cin][cout]: col=l&15 ;
// D: col(cout)=l&15, row(pix)=(l>>4)*4+reg  [m89/m91-verified layout].
__global__ __launch_bounds__(256) void k_stem_mfma(
    const float* __restrict__ feat,   // [8][256][H][W] fp32
    const unsigned short* __restrict__ whi,
    const unsigned short* __restrict__ wlo,
    const float* __restrict__ bstem,
    const float* __restrict__ wobj, const float* __restrict__ bobj,
    const float* __restrict__ wbox, const float* __restrict__ bbox,
    float* __restrict__ scores,       // [8][H*W*3]
    float* __restrict__ deltas,       // [8][H*W*12]
    const int H, const int W)
{
  // A halo tile: 4 rows x 34 cols x 32 cins, stride 40 u16 (80B: 16B-aligned rows,
  // read banks 2-way (free), write 8-way on a tiny pass). hi plane then lo plane.
  __shared__ __align__(16) unsigned short Abuf[2*5440];
  __shared__ float whl[15][256];

  const int tid = threadIdx.x;
  const int l = tid & 63, w = tid >> 6;
  const int li = l & 15, g = l >> 4;
  const int wrow = w >> 1, wcol = w & 1;
  const int px0 = blockIdx.x * 32, py0 = blockIdx.y * 2;
  const int b = blockIdx.z;
  const size_t HW = (size_t)H * W;
  const float* fb = feat + (size_t)b * 256 * HW;

  // head weights -> LDS (consumed only after many barriers)
  for (int i = tid; i < 15*256; i += 256){
    const int oc = i >> 8, c = i & 255;
    whl[oc][c] = (oc < 3) ? wobj[oc*256 + c] : wbox[(oc-3)*256 + c];
  }

  f32x4 acc[16];
#pragma unroll
  for (int i = 0; i < 16; ++i) acc[i] = (f32x4){0.f, 0.f, 0.f, 0.f};

  for (int slice = 0; slice < 8; ++slice){
    __syncthreads();                       // previous slice's A reads done
    // stage halo tile (4x34x32 fp32 -> hi/lo bf16). 4352 = 17*256 values.
#pragma unroll
    for (int v = 0; v < 17; ++v){
      const int idx = v*256 + tid;
      const int cin = idx / 136;
      const int pl  = idx - cin*136;
      const int gr  = pl / 34;
      const int gc  = pl - gr*34;
      const int row = py0 + gr - 1, col = px0 + gc - 1;
      float x = 0.f;
      if (row >= 0 && row < H && col >= 0 && col < W)
        x = fb[(size_t)(slice*32 + cin)*HW + (size_t)row*W + col];
      const unsigned short h = f2bf(x);
      const unsigned short lo2 = f2bf(x - bf2f(h));
      Abuf[pl*40 + cin] = h;
      Abuf[5440 + pl*40 + cin] = lo2;
    }
    __syncthreads();

#pragma unroll
    for (int tap = 0; tap < 9; ++tap){
      const int dr = tap/3 - 1, dc = tap - (tap/3)*3 - 1;   // constants after unroll
      const int aoff = ((wrow + dr + 1)*34 + (wcol*16 + li + dc + 1))*40 + g*8;
      const s8b ahi = *reinterpret_cast<const s8b*>(&Abuf[aoff]);
      const s8b alo = *reinterpret_cast<const s8b*>(&Abuf[5440 + aoff]);
#pragma unroll
      for (int nc = 0; nc < 4; ++nc){
        s8b bh[4], bl[4];
#pragma unroll
        for (int cg = 0; cg < 4; ++cg){
          const int cout = nc*64 + cg*16 + li;
          const size_t woff = ((((size_t)tap*8 + slice)*4 + g)*256 + cout)*8;
          bh[cg] = *reinterpret_cast<const s8b*>(&whi[woff]);
          bl[cg] = *reinterpret_cast<const s8b*>(&wlo[woff]);
        }
#pragma unroll
        for (int cg = 0; cg < 4; ++cg)
          acc[nc*4+cg] = __builtin_amdgcn_mfma_f32_16x16x32_bf16(ahi, bh[cg], acc[nc*4+cg], 0, 0, 0);
#pragma unroll
        for (int cg = 0; cg < 4; ++cg)
          acc[nc*4+cg] = __builtin_amdgcn_mfma_f32_16x16x32_bf16(ahi, bl[cg], acc[nc*4+cg], 0, 0, 0);
#pragma unroll
        for (int cg = 0; cg < 4; ++cg)
          acc[nc*4+cg] = __builtin_amdgcn_mfma_f32_16x16x32_bf16(alo, bh[cg], acc[nc*4+cg], 0, 0, 0);
      }
    }
  }

  // bias + relu (cout = f*16 + li)
#pragma unroll
  for (int f = 0; f < 16; ++f){
    const float bsv = bstem[f*16 + li];
#pragma unroll
    for (int r = 0; r < 4; ++r) acc[f][r] = fmaxf(acc[f][r] + bsv, 0.f);
  }

  // heads: per-wave private x_q (16 pix x 65 f32) overlaid on Abuf
  float* xq = reinterpret_cast<float*>(Abuf);
  float s[15];
#pragma unroll
  for (int oc = 0; oc < 15; ++oc) s[oc] = 0.f;
  const int pix = l >> 2, ch4 = l & 3;
  __syncthreads();                          // all conv reads of Abuf complete
#pragma unroll
  for (int q = 0; q < 4; ++q){
#pragma unroll
    for (int fi = 0; fi < 4; ++fi){
#pragma unroll
      for (int r = 0; r < 4; ++r)
        xq[w*1040 + (g*4 + r)*65 + fi*16 + li] = acc[q*4 + fi][r];
    }
    __syncthreads();
#pragma unroll
    for (int c = 0; c < 16; ++c){
      const float xv = xq[w*1040 + pix*65 + ch4*16 + c];
#pragma unroll
      for (int oc = 0; oc < 15; ++oc)
        s[oc] = fmaf(xv, whl[oc][q*64 + ch4*16 + c], s[oc]);
    }
    __syncthreads();
  }
#pragma unroll
  for (int oc = 0; oc < 15; ++oc){
    s[oc] += __shfl_xor(s[oc], 1, 64);
    s[oc] += __shfl_xor(s[oc], 2, 64);
  }
  if (ch4 == 0){
    const int py = py0 + wrow, px = px0 + wcol*16 + pix;
    const size_t loc = (size_t)py*W + px;
#pragma unroll
    for (int oc = 0; oc < 15; ++oc){
      const float v = s[oc] + ((oc < 3) ? bobj[oc] : bbox[oc-3]);
      if (oc < 3) scores[b*HW*3 + loc*3 + oc] = v;
      else        deltas[b*HW*12 + loc*12 + (oc-3)] = v;
    }
  }
}

// ---------------- per (level,image): top-400 -> decode -> NMS -> top-50 ----------------
__global__ __launch_bounds__(1024) void k_select(
    const float* __restrict__ sc3, const float* __restrict__ sc4, const float* __restrict__ sc5,
    const float* __restrict__ dl3, const float* __restrict__ dl4, const float* __restrict__ dl5,
    float* __restrict__ out)
{
  const int lvl = blockIdx.x >> 3;
  const int b   = blockIdx.x & 7;
  int N, W; float stride; const float* sc; const float* dl;
  if (lvl==0){ N=49152; W=128; stride=8.f;  sc=sc3; dl=dl3; }
  else if (lvl==1){ N=12288; W=64; stride=16.f; sc=sc4; dl=dl4; }
  else { N=3072; W=32; stride=32.f; sc=sc5; dl=dl5; }
  sc += (size_t)b*N;
  dl += (size_t)b*(size_t)(N/3)*12;

  __shared__ unsigned hist[256];
  __shared__ unsigned s_prefix;
  __shared__ int s_need;
  __shared__ int s_cntc;
  __shared__ unsigned long long cand[1024];
  __shared__ int tk[400];
  __shared__ float bx1[400], by1[400], bx2[400], by2[400], bar_[400];
  __shared__ unsigned long long mask[400][7];
  __shared__ int olist[50];

  const int t = threadIdx.x;

  if (t==0){ s_prefix=0u; s_need=400; }
  for (int pass=0; pass<4; ++pass){
    const int shift = 24 - 8*pass;
    if (t<256) hist[t]=0u;
    __syncthreads();
    const unsigned pref = s_prefix;
    for (int i=t; i<N; i+=1024){
      const unsigned k = okey(sc[i]);
      if (pass==0 || (k >> (shift+8)) == pref)
        atomicAdd(&hist[(k>>shift)&255u], 1u);
    }
    __syncthreads();
    if (t==0){
      int need = s_need, cum=0, bsel=0;
      for (int bb=255; bb>=0; --bb){
        const int h = (int)hist[bb];
        if (cum + h >= need){ bsel=bb; break; }
        cum += h;
      }
      s_prefix = (pref<<8) | (unsigned)bsel;
      s_need = need - cum;
    }
    __syncthreads();
  }
  const unsigned K = s_prefix;

  if (t==0) s_cntc = 0;
  cand[t] = 0ull;
  __syncthreads();
  for (int i=t; i<N; i+=1024){
    const unsigned k = okey(sc[i]);
    if (k >= K){
      const int pos = atomicAdd(&s_cntc, 1);
      if (pos < 1024)
        cand[pos] = ((unsigned long long)k<<32) | (unsigned long long)(0xFFFFFFFFu - (unsigned)i);
    }
  }
  __syncthreads();

  for (int kk=2; kk<=1024; kk<<=1){
    for (int j=kk>>1; j>0; j>>=1){
      const int ixj = t ^ j;
      if (ixj > t){
        const unsigned long long a = cand[t], c = cand[ixj];
        const bool descending = ((t & kk) == 0);
        if ((a < c) == descending){ cand[t]=c; cand[ixj]=a; }
      }
      __syncthreads();
    }
  }

  if (t < 400){
    const unsigned long long c = cand[t];
    const int gi = (int)(0xFFFFFFFFu - (unsigned)(c & 0xFFFFFFFFull));
    tk[t] = gi;
    const int loc = gi/3, a = gi - loc*3;
    const int hh = loc / W, ww = loc - hh*W;
    const float cx = (ww + 0.5f)*stride, cy = (hh + 0.5f)*stride;
    const float size = stride*8.f;
    const float sq = (a==0) ? SQH : ((a==1) ? 1.f : SQ2);
    const float hw_ = 0.5f*(size/sq);
    const float hv_ = 0.5f*(size*sq);
    const float ax1 = cx - hw_, ax2 = cx + hw_;
    const float ay1 = cy - hv_, ay2 = cy + hv_;
    const float aw = ax2 - ax1, ah = ay2 - ay1;
    const float acx = ax1 + 0.5f*aw, acy = ay1 + 0.5f*ah;
    const float* dd = dl + (size_t)loc*12 + a*4;
    const float dx = dd[0], dy = dd[1];
    const float dw = fminf(fmaxf(dd[2], -BBOX_CLAMP), BBOX_CLAMP);
    const float dh = fminf(fmaxf(dd[3], -BBOX_CLAMP), BBOX_CLAMP);
    const float pcx = acx + dx*aw;
    const float pcy = acy + dy*ah;
    const float pw = aw*expf(dw);
    const float ph = ah*expf(dh);
    const float x1 = pcx - 0.5f*pw, y1 = pcy - 0.5f*ph;
    const float x2 = pcx + 0.5f*pw, y2 = pcy + 0.5f*ph;
    bx1[t]=x1; by1[t]=y1; bx2[t]=x2; by2[t]=y2;
    bar_[t] = fmaxf(x2-x1, 0.f)*fmaxf(y2-y1, 0.f);
  }
  __syncthreads();

  for (int task=t; task<2800; task+=1024){
    const int i = task/7, w = task - (task/7)*7;
    unsigned long long m = 0ull;
    const float xi1=bx1[i], yi1=by1[i], xi2=bx2[i], yi2=by2[i], ai=bar_[i];
    const int j0 = w<<6;
    const int js = (j0 > i+1) ? j0 : (i+1);
    const int je = (j0+64 < 400) ? (j0+64) : 400;
    for (int j=js; j<je; ++j){
      const float ix1 = fmaxf(xi1, bx1[j]);
      const float iy1 = fmaxf(yi1, by1[j]);
      const float ix2 = fminf(xi2, bx2[j]);
      const float iy2 = fminf(yi2, by2[j]);
      const float inter = fmaxf(ix2-ix1, 0.f)*fmaxf(iy2-iy1, 0.f);
      const float iou = inter / fmaxf(ai + bar_[j] - inter, 1e-8f);
      if (iou > 0.6f) m |= (1ull << (j - j0));
    }
    mask[i][w] = m;
  }
  __syncthreads();

  if (t==0){
    unsigned long long keepw[7];
#pragma unroll
    for (int w=0;w<7;++w) keepw[w] = ~0ull;
    for (int i=0;i<400;++i){
      if ((keepw[i>>6] >> (i&63)) & 1ull){
#pragma unroll
        for (int w=0;w<7;++w) keepw[w] &= ~mask[i][w];
      }
    }
    int cnt=0;
    for (int i=0;i<400 && cnt<50;++i) if ( (keepw[i>>6]>>(i&63)) & 1ull) olist[cnt++]=i;
    for (int i=0;i<400 && cnt<50;++i) if (!((keepw[i>>6]>>(i&63)) & 1ull)) olist[cnt++]=i;
  }
  __syncthreads();

  if (t < 50){
    const int j = olist[t];
    float* o = out + (size_t)b*600 + (size_t)(lvl*50 + t)*4;
    o[0]=bx1[j]; o[1]=by1[j]; o[2]=bx2[j]; o[3]=by2[j];
  }
}

extern "C" void kernel_launch(void* const* d_in, const int* in_sizes, int n_in,
                              void* d_out, int out_size, void* d_ws, size_t ws_size,
                              hipStream_t stream) {
  (void)in_sizes; (void)n_in; (void)out_size; (void)ws_size;
  const float* p3     = (const float*)d_in[0];
  const float* p4     = (const float*)d_in[1];
  const float* p5     = (const float*)d_in[2];
  const float* w_stem = (const float*)d_in[3];
  const float* b_stem = (const float*)d_in[4];
  const float* w_obj  = (const float*)d_in[5];
  const float* b_obj  = (const float*)d_in[6];
  const float* w_box  = (const float*)d_in[7];
  const float* b_box  = (const float*)d_in[8];
  float* out = (float*)d_out;

  unsigned short* whi = (unsigned short*)d_ws;         // 589824 u16
  unsigned short* wlo = whi + 589824;                  // 589824 u16
  float* sc3 = (float*)(wlo + 589824);                 // 8*128*128*3 = 393216
  float* sc4 = sc3 + 393216;                           // 98304
  float* sc5 = sc4 + 98304;                            // 24576
  float* dl3 = sc5 + 24576;                            // 1572864
  float* dl4 = dl3 + 1572864;                          // 393216
  float* dl5 = dl4 + 393216;                           // 98304

  k_wsplit<<<dim3(2304), dim3(256), 0, stream>>>(w_stem, whi, wlo);

  k_stem_mfma<<<dim3(4, 64, 8), dim3(256), 0, stream>>>(p3, whi, wlo, b_stem, w_obj, b_obj, w_box, b_box, sc3, dl3, 128, 128);
  k_stem_mfma<<<dim3(2, 32, 8), dim3(256), 0, stream>>>(p4, whi, wlo, b_stem, w_obj, b_obj, w_box, b_box, sc4, dl4, 64, 64);
  k_stem_mfma<<<dim3(1, 16, 8), dim3(256), 0, stream>>>(p5, whi, wlo, b_stem, w_obj, b_obj, w_box, b_box, sc5, dl5, 32, 32);

  k_select<<<dim3(24), dim3(1024), 0, stream>>>(sc3, sc4, sc5, dl3, dl4, dl5, out);
}

// Round 9
// 1471.885 us; speedup vs baseline: 2.7932x; 2.7932x over previous
//
#include <hip/hip_runtime.h>
#include <math.h>
#include <stdint.h>

#define BBOX_CLAMP 4.135166556742356f
#define SQH 0.70710678118654752f
#define SQ2 1.41421356237309515f

typedef __attribute__((ext_vector_type(8))) short s8b;
typedef __attribute__((ext_vector_type(4))) float f32x4;

__device__ __forceinline__ unsigned okey(float f){
  unsigned u = __float_as_uint(f);
  return (u & 0x80000000u) ? ~u : (u | 0x80000000u);
}
__device__ __forceinline__ unsigned short f2bf(float f){  // RNE fp32->bf16
  unsigned u = __float_as_uint(f);
  unsigned r = (u + 0x7FFFu + ((u >> 16) & 1u)) >> 16;
  return (unsigned short)r;
}
__device__ __forceinline__ float bf2f(unsigned short h){
  return __uint_as_float(((unsigned)h) << 16);
}

// ---- one-time: split stem weights into bf16 hi/lo, MFMA-B-fragment layout ----
// whi/wlo[(((tap*8+slice)*4+g)*256 + cout)*8 + j] = split of w[cout][cin=slice*32+g*8+j][tap]
__global__ void k_wsplit(const float* __restrict__ w,
                         unsigned short* __restrict__ whi, unsigned short* __restrict__ wlo){
  const int ck = blockIdx.x;          // cin*9 + tap
  const int cout = threadIdx.x;
  const int cin = ck / 9, tap = ck - cin*9;
  const float x = w[cout*2304 + ck];
  const unsigned short h = f2bf(x);
  const unsigned short lo2 = f2bf(x - bf2f(h));
  const int slice = cin >> 5, g = (cin >> 3) & 3, j = cin & 7;
  const size_t off = ((((size_t)tap*8 + slice)*4 + g)*256 + cout)*8 + j;
  whi[off] = h; wlo[off] = lo2;
}

// ---- fused stem conv3x3 (split-bf16 MFMA) + bias + relu + obj/box heads ----
// One launch for all 3 levels (1344 blocks). Block: 4 waves, 128 px (4 rows x 32
// cols); wave w owns couts [64w,64w+64) for ALL 128 px (8 Mgrp x 4 cg acc) ->
// each 8KB B-batch feeds 96 MFMAs (fixes r8's 1-MFMA-per-KB L2-bound regime),
// and waves load disjoint B (no 4x redundancy). Per-acc chain: slice asc -> tap
// asc -> (hihi,hilo,lohi) — identical to r8's passing order. Layouts (A row=li,
// k=g*8+j; B col=li; D col=li,row=g*4+r) are r8-hardware-verified.
__global__ __launch_bounds__(256) void k_stem_mfma(
    const float* __restrict__ p3f, const float* __restrict__ p4f, const float* __restrict__ p5f,
    const unsigned short* __restrict__ whi, const unsigned short* __restrict__ wlo,
    const float* __restrict__ bstem,
    const float* __restrict__ wobj, const float* __restrict__ bobj,
    const float* __restrict__ wbox, const float* __restrict__ bbox,
    float* __restrict__ sc3, float* __restrict__ dl3,
    float* __restrict__ sc4, float* __restrict__ dl4,
    float* __restrict__ sc5, float* __restrict__ dl5)
{
  // union: A halo tile (2 planes x 204 pl x 40 u16 = 32640 B) / head partials
  // (4 x 128 x 17 f32 = 34816 B)
  __shared__ __align__(16) unsigned char smem[34816];
  unsigned short* Abuf = reinterpret_cast<unsigned short*>(smem);
  float* part = reinterpret_cast<float*>(smem);

  const int tid = threadIdx.x;
  const int l = tid & 63, w = tid >> 6;
  const int li = l & 15, g = l >> 4;

  // ---- level decode ----
  int id = blockIdx.x;
  const float* feat; float* scores; float* deltas; int H, W, bx, by, b;
  if (id < 1024){ feat=p3f; scores=sc3; deltas=dl3; H=128; W=128;
      bx = id & 3; by = (id >> 2) & 31; b = id >> 7; }
  else if (id < 1280){ id -= 1024; feat=p4f; scores=sc4; deltas=dl4; H=64; W=64;
      bx = id & 1; by = (id >> 1) & 15; b = id >> 5; }
  else { id -= 1280; feat=p5f; scores=sc5; deltas=dl5; H=32; W=32;
      bx = 0; by = id & 7; b = id >> 3; }
  const int px0 = bx*32, py0 = by*4;
  const size_t HW = (size_t)H*W;
  const float* fb = feat + (size_t)b*256*HW;

  // ---- staging map (computed once): thread = halo pixel, iter = cin ----
  const int gr = tid / 34, gc = tid - gr*34;
  const int row = py0 + gr - 1, col = px0 + gc - 1;
  const bool inb = (tid < 204) && row >= 0 && row < H && col >= 0 && col < W;
  const bool lact = (tid < 204);
  const float* gA = fb + ((size_t)(inb ? row : 0)*W + (inb ? col : 0));

  f32x4 acc[8][4];
#pragma unroll
  for (int m=0;m<8;++m)
#pragma unroll
    for (int cg=0;cg<4;++cg) acc[m][cg] = (f32x4){0.f,0.f,0.f,0.f};

  const int lig = li*40 + g*8;

  for (int slice = 0; slice < 8; ++slice){
    __syncthreads();                      // prior slice's A reads done
    const float* gs = gA + (size_t)slice*32*HW;
#pragma unroll
    for (int i = 0; i < 32; ++i){
      float x = 0.f;
      if (inb) x = gs[(size_t)i*HW];
      if (lact){
        const unsigned short h = f2bf(x);
        Abuf[tid*40 + i] = h;
        Abuf[8160 + tid*40 + i] = f2bf(x - bf2f(h));
      }
    }
    __syncthreads();

    for (int tap = 0; tap < 9; ++tap){
      const int dr = tap/3 - 1, dc = tap - (tap/3)*3 - 1;
      // this wave's B quarter: couts 64w + cg*16 + li
      s8b bh[4], bl[4];
#pragma unroll
      for (int cg = 0; cg < 4; ++cg){
        const int woff = ((((tap*8 + slice)*4 + g)*256) + (w*64 + cg*16 + li))*8;
        bh[cg] = *reinterpret_cast<const s8b*>(&whi[woff]);
        bl[cg] = *reinterpret_cast<const s8b*>(&wlo[woff]);
      }
      const int tb = (dr*34 + dc)*40;
#pragma unroll
      for (int m = 0; m < 8; ++m){
        const int rm = m >> 1, cm = m & 1;
        const int aoff = ((rm+1)*34 + cm*16 + 1)*40 + lig + tb;
        const s8b ahi = *reinterpret_cast<const s8b*>(&Abuf[aoff]);
        const s8b alo = *reinterpret_cast<const s8b*>(&Abuf[8160 + aoff]);
#pragma unroll
        for (int cg = 0; cg < 4; ++cg){
          acc[m][cg] = __builtin_amdgcn_mfma_f32_16x16x32_bf16(ahi, bh[cg], acc[m][cg], 0, 0, 0);
          acc[m][cg] = __builtin_amdgcn_mfma_f32_16x16x32_bf16(ahi, bl[cg], acc[m][cg], 0, 0, 0);
          acc[m][cg] = __builtin_amdgcn_mfma_f32_16x16x32_bf16(alo, bh[cg], acc[m][cg], 0, 0, 0);
        }
      }
    }
  }

  // ---- bias + relu (cout = w*64 + cg*16 + li) ----
#pragma unroll
  for (int cg = 0; cg < 4; ++cg){
    const float bsv = bstem[w*64 + cg*16 + li];
#pragma unroll
    for (int m = 0; m < 8; ++m)
#pragma unroll
      for (int r = 0; r < 4; ++r)
        acc[m][cg][r] = fmaxf(acc[m][cg][r] + bsv, 0.f);
  }

  __syncthreads();                        // conv A reads done; smem -> partials

  // ---- head partials: wave-local 64-cout dot, 16-lane shuffle tree ----
#pragma unroll
  for (int oc = 0; oc < 15; ++oc){
    float wv[4];
#pragma unroll
    for (int cg = 0; cg < 4; ++cg){
      const int cc = w*64 + cg*16 + li;
      wv[cg] = (oc < 3) ? wobj[oc*256 + cc] : wbox[(oc-3)*256 + cc];
    }
#pragma unroll
    for (int m = 0; m < 8; ++m){
#pragma unroll
      for (int r = 0; r < 4; ++r){
        float t = acc[m][0][r] * wv[0];
        t = fmaf(acc[m][1][r], wv[1], t);
        t = fmaf(acc[m][2][r], wv[2], t);
        t = fmaf(acc[m][3][r], wv[3], t);
        t += __shfl_xor(t, 1, 64);
        t += __shfl_xor(t, 2, 64);
        t += __shfl_xor(t, 4, 64);
        t += __shfl_xor(t, 8, 64);
        if (li == 0){
          const int rm = m >> 1, cm = m & 1;
          const int px = rm*32 + cm*16 + g*4 + r;
          part[(w*128 + px)*17 + oc] = t;
        }
      }
    }
  }
  __syncthreads();

  // ---- combine quarters (fixed order) + bias, write scores/deltas ----
  {
    const int px = tid & 127, half = tid >> 7;
    const int rm2 = px >> 5, rem = px & 31;
    const int hh = py0 + rm2, ww = px0 + rem;
    const size_t loc = (size_t)hh*W + ww;
    const int oce = half ? 15 : 8;
    for (int oc = half*8; oc < oce; ++oc){
      float s = ((part[(0*128+px)*17+oc] + part[(1*128+px)*17+oc])
               +  part[(2*128+px)*17+oc]) + part[(3*128+px)*17+oc];
      s += (oc < 3) ? bobj[oc] : bbox[oc-3];
      if (oc < 3) scores[(size_t)b*HW*3 + loc*3 + oc] = s;
      else        deltas[(size_t)b*HW*12 + loc*12 + (oc-3)] = s;
    }
  }
}

// ---------------- per (level,image): top-400 -> decode -> NMS -> top-50 ----------------
__global__ __launch_bounds__(1024) void k_select(
    const float* __restrict__ sc3, const float* __restrict__ sc4, const float* __restrict__ sc5,
    const float* __restrict__ dl3, const float* __restrict__ dl4, const float* __restrict__ dl5,
    float* __restrict__ out)
{
  const int lvl = blockIdx.x >> 3;
  const int b   = blockIdx.x & 7;
  int N, W; float stride; const float* sc; const float* dl;
  if (lvl==0){ N=49152; W=128; stride=8.f;  sc=sc3; dl=dl3; }
  else if (lvl==1){ N=12288; W=64; stride=16.f; sc=sc4; dl=dl4; }
  else { N=3072; W=32; stride=32.f; sc=sc5; dl=dl5; }
  sc += (size_t)b*N;
  dl += (size_t)b*(size_t)(N/3)*12;

  __shared__ unsigned hist[256];
  __shared__ unsigned s_prefix;
  __shared__ int s_need;
  __shared__ int s_cntc;
  __shared__ unsigned long long cand[1024];
  __shared__ int tk[400];
  __shared__ float bx1[400], by1[400], bx2[400], by2[400], bar_[400];
  __shared__ unsigned long long mask[400][7];
  __shared__ int olist[50];

  const int t = threadIdx.x;

  if (t==0){ s_prefix=0u; s_need=400; }
  for (int pass=0; pass<4; ++pass){
    const int shift = 24 - 8*pass;
    if (t<256) hist[t]=0u;
    __syncthreads();
    const unsigned pref = s_prefix;
    for (int i=t; i<N; i+=1024){
      const unsigned k = okey(sc[i]);
      if (pass==0 || (k >> (shift+8)) == pref)
        atomicAdd(&hist[(k>>shift)&255u], 1u);
    }
    __syncthreads();
    if (t==0){
      int need = s_need, cum=0, bsel=0;
      for (int bb=255; bb>=0; --bb){
        const int h = (int)hist[bb];
        if (cum + h >= need){ bsel=bb; break; }
        cum += h;
      }
      s_prefix = (pref<<8) | (unsigned)bsel;
      s_need = need - cum;
    }
    __syncthreads();
  }
  const unsigned K = s_prefix;

  if (t==0) s_cntc = 0;
  cand[t] = 0ull;
  __syncthreads();
  for (int i=t; i<N; i+=1024){
    const unsigned k = okey(sc[i]);
    if (k >= K){
      const int pos = atomicAdd(&s_cntc, 1);
      if (pos < 1024)
        cand[pos] = ((unsigned long long)k<<32) | (unsigned long long)(0xFFFFFFFFu - (unsigned)i);
    }
  }
  __syncthreads();

  for (int kk=2; kk<=1024; kk<<=1){
    for (int j=kk>>1; j>0; j>>=1){
      const int ixj = t ^ j;
      if (ixj > t){
        const unsigned long long a = cand[t], c = cand[ixj];
        const bool descending = ((t & kk) == 0);
        if ((a < c) == descending){ cand[t]=c; cand[ixj]=a; }
      }
      __syncthreads();
    }
  }

  if (t < 400){
    const unsigned long long c = cand[t];
    const int gi = (int)(0xFFFFFFFFu - (unsigned)(c & 0xFFFFFFFFull));
    tk[t] = gi;
    const int loc = gi/3, a = gi - loc*3;
    const int hh = loc / W, ww = loc - hh*W;
    const float cx = (ww + 0.5f)*stride, cy = (hh + 0.5f)*stride;
    const float size = stride*8.f;
    const float sq = (a==0) ? SQH : ((a==1) ? 1.f : SQ2);
    const float hw_ = 0.5f*(size/sq);
    const float hv_ = 0.5f*(size*sq);
    const float ax1 = cx - hw_, ax2 = cx + hw_;
    const float ay1 = cy - hv_, ay2 = cy + hv_;
    const float aw = ax2 - ax1, ah = ay2 - ay1;
    const float acx = ax1 + 0.5f*aw, acy = ay1 + 0.5f*ah;
    const float* dd = dl + (size_t)loc*12 + a*4;
    const float dx = dd[0], dy = dd[1];
    const float dw = fminf(fmaxf(dd[2], -BBOX_CLAMP), BBOX_CLAMP);
    const float dh = fminf(fmaxf(dd[3], -BBOX_CLAMP), BBOX_CLAMP);
    const float pcx = acx + dx*aw;
    const float pcy = acy + dy*ah;
    const float pw = aw*expf(dw);
    const float ph = ah*expf(dh);
    const float x1 = pcx - 0.5f*pw, y1 = pcy - 0.5f*ph;
    const float x2 = pcx + 0.5f*pw, y2 = pcy + 0.5f*ph;
    bx1[t]=x1; by1[t]=y1; bx2[t]=x2; by2[t]=y2;
    bar_[t] = fmaxf(x2-x1, 0.f)*fmaxf(y2-y1, 0.f);
  }
  __syncthreads();

  for (int task=t; task<2800; task+=1024){
    const int i = task/7, w = task - (task/7)*7;
    unsigned long long m = 0ull;
    const float xi1=bx1[i], yi1=by1[i], xi2=bx2[i], yi2=by2[i], ai=bar_[i];
    const int j0 = w<<6;
    const int js = (j0 > i+1) ? j0 : (i+1);
    const int je = (j0+64 < 400) ? (j0+64) : 400;
    for (int j=js; j<je; ++j){
      const float ix1 = fmaxf(xi1, bx1[j]);
      const float iy1 = fmaxf(yi1, by1[j]);
      const float ix2 = fminf(xi2, bx2[j]);
      const float iy2 = fminf(yi2, by2[j]);
      const float inter = fmaxf(ix2-ix1, 0.f)*fmaxf(iy2-iy1, 0.f);
      const float iou = inter / fmaxf(ai + bar_[j] - inter, 1e-8f);
      if (iou > 0.6f) m |= (1ull << (j - j0));
    }
    mask[i][w] = m;
  }
  __syncthreads();

  if (t==0){
    unsigned long long keepw[7];
#pragma unroll
    for (int w=0;w<7;++w) keepw[w] = ~0ull;
    for (int i=0;i<400;++i){
      if ((keepw[i>>6] >> (i&63)) & 1ull){
#pragma unroll
        for (int w=0;w<7;++w) keepw[w] &= ~mask[i][w];
      }
    }
    int cnt=0;
    for (int i=0;i<400 && cnt<50;++i) if ( (keepw[i>>6]>>(i&63)) & 1ull) olist[cnt++]=i;
    for (int i=0;i<400 && cnt<50;++i) if (!((keepw[i>>6]>>(i&63)) & 1ull)) olist[cnt++]=i;
  }
  __syncthreads();

  if (t < 50){
    const int j = olist[t];
    float* o = out + (size_t)b*600 + (size_t)(lvl*50 + t)*4;
    o[0]=bx1[j]; o[1]=by1[j]; o[2]=bx2[j]; o[3]=by2[j];
  }
}

extern "C" void kernel_launch(void* const* d_in, const int* in_sizes, int n_in,
                              void* d_out, int out_size, void* d_ws, size_t ws_size,
                              hipStream_t stream) {
  (void)in_sizes; (void)n_in; (void)out_size; (void)ws_size;
  const float* p3     = (const float*)d_in[0];
  const float* p4     = (const float*)d_in[1];
  const float* p5     = (const float*)d_in[2];
  const float* w_stem = (const float*)d_in[3];
  const float* b_stem = (const float*)d_in[4];
  const float* w_obj  = (const float*)d_in[5];
  const float* b_obj  = (const float*)d_in[6];
  const float* w_box  = (const float*)d_in[7];
  const float* b_box  = (const float*)d_in[8];
  float* out = (float*)d_out;

  unsigned short* whi = (unsigned short*)d_ws;         // 589824 u16
  unsigned short* wlo = whi + 589824;                  // 589824 u16
  float* sc3 = (float*)(wlo + 589824);                 // 393216
  float* sc4 = sc3 + 393216;                           // 98304
  float* sc5 = sc4 + 98304;                            // 24576
  float* dl3 = sc5 + 24576;                            // 1572864
  float* dl4 = dl3 + 1572864;                          // 393216
  float* dl5 = dl4 + 393216;                           // 98304

  k_wsplit<<<dim3(2304), dim3(256), 0, stream>>>(w_stem, whi, wlo);

  k_stem_mfma<<<dim3(1344), dim3(256), 0, stream>>>(
      p3, p4, p5, whi, wlo, b_stem, w_obj, b_obj, w_box, b_box,
      sc3, dl3, sc4, dl4, sc5, dl5);

  k_select<<<dim3(24), dim3(1024), 0, stream>>>(sc3, sc4, sc5, dl3, dl4, dl5, out);
}

// Round 10
// 832.526 us; speedup vs baseline: 4.9382x; 1.7680x over previous
//
#include <hip/hip_runtime.h>
#include <math.h>
#include <stdint.h>

#define BBOX_CLAMP 4.135166556742356f
#define SQH 0.70710678118654752f
#define SQ2 1.41421356237309515f

typedef __attribute__((ext_vector_type(8))) short s8b;
typedef __attribute__((ext_vector_type(4))) float f32x4;
typedef __attribute__((ext_vector_type(4))) short s4b;

__device__ __forceinline__ unsigned okey(float f){
  unsigned u = __float_as_uint(f);
  return (u & 0x80000000u) ? ~u : (u | 0x80000000u);
}
__device__ __forceinline__ unsigned short f2bf(float f){  // RNE fp32->bf16
  unsigned u = __float_as_uint(f);
  unsigned r = (u + 0x7FFFu + ((u >> 16) & 1u)) >> 16;
  return (unsigned short)r;
}
__device__ __forceinline__ float bf2f(unsigned short h){
  return __uint_as_float(((unsigned)h) << 16);
}

// ---- one-time: split stem weights into bf16 hi/lo, MFMA-B-fragment layout ----
// whi/wlo[(((tap*8+slice)*4+g)*256 + cout)*8 + j] = split of w[cout][cin=slice*32+g*8+j][tap]
__global__ void k_wsplit(const float* __restrict__ w,
                         unsigned short* __restrict__ whi, unsigned short* __restrict__ wlo){
  const int ck = blockIdx.x;          // cin*9 + tap
  const int cout = threadIdx.x;
  const int cin = ck / 9, tap = ck - cin*9;
  const float x = w[cout*2304 + ck];
  const unsigned short h = f2bf(x);
  const unsigned short lo2 = f2bf(x - bf2f(h));
  const int slice = cin >> 5, g = (cin >> 3) & 3, j = cin & 7;
  const size_t off = ((((size_t)tap*8 + slice)*4 + g)*256 + cout)*8 + j;
  whi[off] = h; wlo[off] = lo2;
}

// ---- fused stem conv3x3 (split-bf16 MFMA) + bias + relu + obj/box heads ----
// Block: 4 waves, 128 px; wave w owns couts [64w,64w+64). launch_bounds(256,2):
// 256 regs/wave = 128 arch + 128 acc — acc[8][4]=128 AGPR exactly fits, arch
// live ~110 fits 128 -> 2 waves/SIMD (r9 was 272 regs -> 1 wave/SIMD, all
// latency exposed). r2-r4 spills were min-waves with arch-live > budget/2.
// Per-acc chain: slice asc -> tap asc -> (hihi,hilo,lohi) — r8/r9 passing order.
__global__ __launch_bounds__(256, 2) void k_stem_mfma(
    const float* __restrict__ p3f, const float* __restrict__ p4f, const float* __restrict__ p5f,
    const unsigned short* __restrict__ whi, const unsigned short* __restrict__ wlo,
    const float* __restrict__ bstem,
    const float* __restrict__ wobj, const float* __restrict__ bobj,
    const float* __restrict__ wbox, const float* __restrict__ bbox,
    float* __restrict__ sc3, float* __restrict__ dl3,
    float* __restrict__ sc4, float* __restrict__ dl4,
    float* __restrict__ sc5, float* __restrict__ dl5)
{
  // union: A halo tile (2 planes x 204 pl x 40 u16 = 32640 B) / head partials
  // (4 x 128 x 17 f32 = 34816 B)
  __shared__ __align__(16) unsigned char smem[34816];
  unsigned short* Abuf = reinterpret_cast<unsigned short*>(smem);
  float* part = reinterpret_cast<float*>(smem);

  const int tid = threadIdx.x;
  const int l = tid & 63, w = tid >> 6;
  const int li = l & 15, g = l >> 4;

  // ---- level decode ----
  int id = blockIdx.x;
  const float* feat; float* scores; float* deltas; int H, W, bx, by, b;
  if (id < 1024){ feat=p3f; scores=sc3; deltas=dl3; H=128; W=128;
      bx = id & 3; by = (id >> 2) & 31; b = id >> 7; }
  else if (id < 1280){ id -= 1024; feat=p4f; scores=sc4; deltas=dl4; H=64; W=64;
      bx = id & 1; by = (id >> 1) & 15; b = id >> 5; }
  else { id -= 1280; feat=p5f; scores=sc5; deltas=dl5; H=32; W=32;
      bx = 0; by = id & 7; b = id >> 3; }
  const int px0 = bx*32, py0 = by*4;
  const size_t HW = (size_t)H*W;
  const float* fb = feat + (size_t)b*256*HW;

  // ---- staging map (computed once): thread = halo pixel, iter = cin ----
  const int gr = tid / 34, gc = tid - gr*34;
  const int row = py0 + gr - 1, col = px0 + gc - 1;
  const bool inb = (tid < 204) && row >= 0 && row < H && col >= 0 && col < W;
  const bool lact = (tid < 204);
  const float* gA = fb + ((size_t)(inb ? row : 0)*W + (inb ? col : 0));

  f32x4 acc[8][4];
#pragma unroll
  for (int m=0;m<8;++m)
#pragma unroll
    for (int cg=0;cg<4;++cg) acc[m][cg] = (f32x4){0.f,0.f,0.f,0.f};

  const int lig = li*40 + g*8;

  for (int slice = 0; slice < 8; ++slice){
    __syncthreads();                      // prior slice's A reads done
    const float* gs = gA + (size_t)slice*32*HW;
    // stage 32 cins as 8 chunks of 4, packed b64 writes (4x fewer LDS writes)
#pragma unroll
    for (int ch = 0; ch < 8; ++ch){
      float x0=0.f, x1=0.f, x2=0.f, x3=0.f;
      if (inb){
        x0 = gs[(size_t)(ch*4+0)*HW];
        x1 = gs[(size_t)(ch*4+1)*HW];
        x2 = gs[(size_t)(ch*4+2)*HW];
        x3 = gs[(size_t)(ch*4+3)*HW];
      }
      if (lact){
        const unsigned short h0=f2bf(x0), h1=f2bf(x1), h2=f2bf(x2), h3=f2bf(x3);
        s4b hv; hv[0]=(short)h0; hv[1]=(short)h1; hv[2]=(short)h2; hv[3]=(short)h3;
        s4b lv; lv[0]=(short)f2bf(x0-bf2f(h0)); lv[1]=(short)f2bf(x1-bf2f(h1));
                lv[2]=(short)f2bf(x2-bf2f(h2)); lv[3]=(short)f2bf(x3-bf2f(h3));
        *reinterpret_cast<s4b*>(&Abuf[tid*40 + ch*4]) = hv;
        *reinterpret_cast<s4b*>(&Abuf[8160 + tid*40 + ch*4]) = lv;
      }
    }
    __syncthreads();

    for (int tap = 0; tap < 9; ++tap){
      const int dr = tap/3 - 1, dc = tap - (tap/3)*3 - 1;
      // this wave's B quarter: couts 64w + cg*16 + li
      s8b bh[4], bl[4];
#pragma unroll
      for (int cg = 0; cg < 4; ++cg){
        const int woff = ((((tap*8 + slice)*4 + g)*256) + (w*64 + cg*16 + li))*8;
        bh[cg] = *reinterpret_cast<const s8b*>(&whi[woff]);
        bl[cg] = *reinterpret_cast<const s8b*>(&wlo[woff]);
      }
      const int tb = (dr*34 + dc)*40;
#pragma unroll
      for (int m = 0; m < 8; ++m){
        const int rm = m >> 1, cm = m & 1;
        const int aoff = ((rm+1)*34 + cm*16 + 1)*40 + lig + tb;
        const s8b ahi = *reinterpret_cast<const s8b*>(&Abuf[aoff]);
        const s8b alo = *reinterpret_cast<const s8b*>(&Abuf[8160 + aoff]);
#pragma unroll
        for (int cg = 0; cg < 4; ++cg){
          acc[m][cg] = __builtin_amdgcn_mfma_f32_16x16x32_bf16(ahi, bh[cg], acc[m][cg], 0, 0, 0);
          acc[m][cg] = __builtin_amdgcn_mfma_f32_16x16x32_bf16(ahi, bl[cg], acc[m][cg], 0, 0, 0);
          acc[m][cg] = __builtin_amdgcn_mfma_f32_16x16x32_bf16(alo, bh[cg], acc[m][cg], 0, 0, 0);
        }
      }
    }
  }

  // ---- bias + relu (cout = w*64 + cg*16 + li) ----
#pragma unroll
  for (int cg = 0; cg < 4; ++cg){
    const float bsv = bstem[w*64 + cg*16 + li];
#pragma unroll
    for (int m = 0; m < 8; ++m)
#pragma unroll
      for (int r = 0; r < 4; ++r)
        acc[m][cg][r] = fmaxf(acc[m][cg][r] + bsv, 0.f);
  }

  __syncthreads();                        // conv A reads done; smem -> partials

  // ---- head partials: wave-local 64-cout dot, 16-lane shuffle tree ----
#pragma unroll
  for (int oc = 0; oc < 15; ++oc){
    float wv[4];
#pragma unroll
    for (int cg = 0; cg < 4; ++cg){
      const int cc = w*64 + cg*16 + li;
      wv[cg] = (oc < 3) ? wobj[oc*256 + cc] : wbox[(oc-3)*256 + cc];
    }
#pragma unroll
    for (int m = 0; m < 8; ++m){
#pragma unroll
      for (int r = 0; r < 4; ++r){
        float t = acc[m][0][r] * wv[0];
        t = fmaf(acc[m][1][r], wv[1], t);
        t = fmaf(acc[m][2][r], wv[2], t);
        t = fmaf(acc[m][3][r], wv[3], t);
        t += __shfl_xor(t, 1, 64);
        t += __shfl_xor(t, 2, 64);
        t += __shfl_xor(t, 4, 64);
        t += __shfl_xor(t, 8, 64);
        if (li == 0){
          const int rm = m >> 1, cm = m & 1;
          const int px = rm*32 + cm*16 + g*4 + r;
          part[(w*128 + px)*17 + oc] = t;
        }
      }
    }
  }
  __syncthreads();

  // ---- combine quarters (fixed order) + bias, write scores/deltas ----
  {
    const int px = tid & 127, half = tid >> 7;
    const int rm2 = px >> 5, rem = px & 31;
    const int hh = py0 + rm2, ww = px0 + rem;
    const size_t loc = (size_t)hh*W + ww;
    const int oce = half ? 15 : 8;
    for (int oc = half*8; oc < oce; ++oc){
      float s = ((part[(0*128+px)*17+oc] + part[(1*128+px)*17+oc])
               +  part[(2*128+px)*17+oc]) + part[(3*128+px)*17+oc];
      s += (oc < 3) ? bobj[oc] : bbox[oc-3];
      if (oc < 3) scores[(size_t)b*HW*3 + loc*3 + oc] = s;
      else        deltas[(size_t)b*HW*12 + loc*12 + (oc-3)] = s;
    }
  }
}

// ---------------- per (level,image): top-400 -> decode -> NMS -> top-50 ----------------
__global__ __launch_bounds__(1024) void k_select(
    const float* __restrict__ sc3, const float* __restrict__ sc4, const float* __restrict__ sc5,
    const float* __restrict__ dl3, const float* __restrict__ dl4, const float* __restrict__ dl5,
    float* __restrict__ out)
{
  const int lvl = blockIdx.x >> 3;
  const int b   = blockIdx.x & 7;
  int N, W; float stride; const float* sc; const float* dl;
  if (lvl==0){ N=49152; W=128; stride=8.f;  sc=sc3; dl=dl3; }
  else if (lvl==1){ N=12288; W=64; stride=16.f; sc=sc4; dl=dl4; }
  else { N=3072; W=32; stride=32.f; sc=sc5; dl=dl5; }
  sc += (size_t)b*N;
  dl += (size_t)b*(size_t)(N/3)*12;

  __shared__ unsigned hist[256];
  __shared__ unsigned s_prefix;
  __shared__ int s_need;
  __shared__ int s_cntc;
  __shared__ unsigned long long cand[1024];
  __shared__ int tk[400];
  __shared__ float bx1[400], by1[400], bx2[400], by2[400], bar_[400];
  __shared__ unsigned long long mask[400][7];
  __shared__ int olist[50];

  const int t = threadIdx.x;

  if (t==0){ s_prefix=0u; s_need=400; }
  for (int pass=0; pass<4; ++pass){
    const int shift = 24 - 8*pass;
    if (t<256) hist[t]=0u;
    __syncthreads();
    const unsigned pref = s_prefix;
    for (int i=t; i<N; i+=1024){
      const unsigned k = okey(sc[i]);
      if (pass==0 || (k >> (shift+8)) == pref)
        atomicAdd(&hist[(k>>shift)&255u], 1u);
    }
    __syncthreads();
    if (t==0){
      int need = s_need, cum=0, bsel=0;
      for (int bb=255; bb>=0; --bb){
        const int h = (int)hist[bb];
        if (cum + h >= need){ bsel=bb; break; }
        cum += h;
      }
      s_prefix = (pref<<8) | (unsigned)bsel;
      s_need = need - cum;
    }
    __syncthreads();
  }
  const unsigned K = s_prefix;

  if (t==0) s_cntc = 0;
  cand[t] = 0ull;
  __syncthreads();
  for (int i=t; i<N; i+=1024){
    const unsigned k = okey(sc[i]);
    if (k >= K){
      const int pos = atomicAdd(&s_cntc, 1);
      if (pos < 1024)
        cand[pos] = ((unsigned long long)k<<32) | (unsigned long long)(0xFFFFFFFFu - (unsigned)i);
    }
  }
  __syncthreads();

  for (int kk=2; kk<=1024; kk<<=1){
    for (int j=kk>>1; j>0; j>>=1){
      const int ixj = t ^ j;
      if (ixj > t){
        const unsigned long long a = cand[t], c = cand[ixj];
        const bool descending = ((t & kk) == 0);
        if ((a < c) == descending){ cand[t]=c; cand[ixj]=a; }
      }
      __syncthreads();
    }
  }

  if (t < 400){
    const unsigned long long c = cand[t];
    const int gi = (int)(0xFFFFFFFFu - (unsigned)(c & 0xFFFFFFFFull));
    tk[t] = gi;
    const int loc = gi/3, a = gi - loc*3;
    const int hh = loc / W, ww = loc - hh*W;
    const float cx = (ww + 0.5f)*stride, cy = (hh + 0.5f)*stride;
    const float size = stride*8.f;
    const float sq = (a==0) ? SQH : ((a==1) ? 1.f : SQ2);
    const float hw_ = 0.5f*(size/sq);
    const float hv_ = 0.5f*(size*sq);
    const float ax1 = cx - hw_, ax2 = cx + hw_;
    const float ay1 = cy - hv_, ay2 = cy + hv_;
    const float aw = ax2 - ax1, ah = ay2 - ay1;
    const float acx = ax1 + 0.5f*aw, acy = ay1 + 0.5f*ah;
    const float* dd = dl + (size_t)loc*12 + a*4;
    const float dx = dd[0], dy = dd[1];
    const float dw = fminf(fmaxf(dd[2], -BBOX_CLAMP), BBOX_CLAMP);
    const float dh = fminf(fmaxf(dd[3], -BBOX_CLAMP), BBOX_CLAMP);
    const float pcx = acx + dx*aw;
    const float pcy = acy + dy*ah;
    const float pw = aw*expf(dw);
    const float ph = ah*expf(dh);
    const float x1 = pcx - 0.5f*pw, y1 = pcy - 0.5f*ph;
    const float x2 = pcx + 0.5f*pw, y2 = pcy + 0.5f*ph;
    bx1[t]=x1; by1[t]=y1; bx2[t]=x2; by2[t]=y2;
    bar_[t] = fmaxf(x2-x1, 0.f)*fmaxf(y2-y1, 0.f);
  }
  __syncthreads();

  for (int task=t; task<2800; task+=1024){
    const int i = task/7, w = task - (task/7)*7;
    unsigned long long m = 0ull;
    const float xi1=bx1[i], yi1=by1[i], xi2=bx2[i], yi2=by2[i], ai=bar_[i];
    const int j0 = w<<6;
    const int js = (j0 > i+1) ? j0 : (i+1);
    const int je = (j0+64 < 400) ? (j0+64) : 400;
    for (int j=js; j<je; ++j){
      const float ix1 = fmaxf(xi1, bx1[j]);
      const float iy1 = fmaxf(yi1, by1[j]);
      const float ix2 = fminf(xi2, bx2[j]);
      const float iy2 = fminf(yi2, by2[j]);
      const float inter = fmaxf(ix2-ix1, 0.f)*fmaxf(iy2-iy1, 0.f);
      const float iou = inter / fmaxf(ai + bar_[j] - inter, 1e-8f);
      if (iou > 0.6f) m |= (1ull << (j - j0));
    }
    mask[i][w] = m;
  }
  __syncthreads();

  if (t==0){
    unsigned long long keepw[7];
#pragma unroll
    for (int w=0;w<7;++w) keepw[w] = ~0ull;
    for (int i=0;i<400;++i){
      if ((keepw[i>>6] >> (i&63)) & 1ull){
#pragma unroll
        for (int w=0;w<7;++w) keepw[w] &= ~mask[i][w];
      }
    }
    int cnt=0;
    for (int i=0;i<400 && cnt<50;++i) if ( (keepw[i>>6]>>(i&63)) & 1ull) olist[cnt++]=i;
    for (int i=0;i<400 && cnt<50;++i) if (!((keepw[i>>6]>>(i&63)) & 1ull)) olist[cnt++]=i;
  }
  __syncthreads();

  if (t < 50){
    const int j = olist[t];
    float* o = out + (size_t)b*600 + (size_t)(lvl*50 + t)*4;
    o[0]=bx1[j]; o[1]=by1[j]; o[2]=bx2[j]; o[3]=by2[j];
  }
}

extern "C" void kernel_launch(void* const* d_in, const int* in_sizes, int n_in,
                              void* d_out, int out_size, void* d_ws, size_t ws_size,
                              hipStream_t stream) {
  (void)in_sizes; (void)n_in; (void)out_size; (void)ws_size;
  const float* p3     = (const float*)d_in[0];
  const float* p4     = (const float*)d_in[1];
  const float* p5     = (const float*)d_in[2];
  const float* w_stem = (const float*)d_in[3];
  const float* b_stem = (const float*)d_in[4];
  const float* w_obj  = (const float*)d_in[5];
  const float* b_obj  = (const float*)d_in[6];
  const float* w_box  = (const float*)d_in[7];
  const float* b_box  = (const float*)d_in[8];
  float* out = (float*)d_out;

  unsigned short* whi = (unsigned short*)d_ws;         // 589824 u16
  unsigned short* wlo = whi + 589824;                  // 589824 u16
  float* sc3 = (float*)(wlo + 589824);                 // 393216
  float* sc4 = sc3 + 393216;                           // 98304
  float* sc5 = sc4 + 98304;                            // 24576
  float* dl3 = sc5 + 24576;                            // 1572864
  float* dl4 = dl3 + 1572864;                          // 393216
  float* dl5 = dl4 + 393216;                           // 98304

  k_wsplit<<<dim3(2304), dim3(256), 0, stream>>>(w_stem, whi, wlo);

  k_stem_mfma<<<dim3(1344), dim3(256), 0, stream>>>(
      p3, p4, p5, whi, wlo, b_stem, w_obj, b_obj, w_box, b_box,
      sc3, dl3, sc4, dl4, sc5, dl5);

  k_select<<<dim3(24), dim3(1024), 0, stream>>>(sc3, sc4, sc5, dl3, dl4, dl5, out);
}